// Round 5
// baseline (417.343 us; speedup 1.0000x reference)
//
#include <hip/hip_runtime.h>

#define N_NODES 100000
#define E_EDGES 1600000
#define C 128     // IN_C = H1 = H2
#define OUTC 64
#define ZROW N_NODES   // index of the dedicated all-zero Hb row

// ---- CSR build (two-level counting sort) constants ----
#define NPB 128                                   // nodes per bucket (dest >> 7)
#define NBKT ((N_NODES + NPB - 1) / NPB)          // 782 buckets
#define CB_BLOCKS 64                              // phase A/C blocks
#define CB_THREADS 1024
#define EPB ((E_EDGES + CB_BLOCKS - 1) / CB_BLOCKS)  // 25000 edges/block
#define SCM (NBKT * CB_BLOCKS)                    // 50048 scan elements
#define S1B 1024
#define NSB ((SCM + S1B - 1) / S1B)               // 49

typedef __attribute__((ext_vector_type(8))) short bf16x8;
typedef __attribute__((ext_vector_type(4))) float f32x4;
typedef __attribute__((ext_vector_type(2))) float f32x2;

// rne float->bf16
__device__ inline unsigned short f2bf(float x) {
    unsigned u = __float_as_uint(x);
    unsigned r = u + 0x7fffu + ((u >> 16) & 1u);
    return (unsigned short)(r >> 16);
}

// ---------------- zero the dedicated ZROW of Hb ----------------
__global__ __launch_bounds__(64) void k_zrow(uint4* __restrict__ Hb4) {
    if (threadIdx.x < 16)
        Hb4[(size_t)ZROW * 16 + threadIdx.x] = make_uint4(0u, 0u, 0u, 0u);
}

// ---------------- Phase A: per-block bucket histogram ----------------
__global__ __launch_bounds__(CB_THREADS) void k_hist(const int* __restrict__ coli,
                                                     int* __restrict__ histG) {
    __shared__ int h[NBKT];
    for (int i = threadIdx.x; i < NBKT; i += CB_THREADS) h[i] = 0;
    __syncthreads();
    const int e0 = blockIdx.x * EPB;
    const int e1 = min(e0 + EPB, E_EDGES);
    for (int e = e0 + (int)threadIdx.x; e < e1; e += CB_THREADS)
        atomicAdd(&h[coli[e] >> 7], 1);
    __syncthreads();
    for (int i = threadIdx.x; i < NBKT; i += CB_THREADS)
        histG[i * CB_BLOCKS + blockIdx.x] = h[i];      // bucket-major
}

// ---------------- Phase B: exclusive scan of histG[SCM] ----------------
__global__ __launch_bounds__(S1B) void k_scanA(const int* __restrict__ in,
                                               int* __restrict__ base,
                                               int* __restrict__ bsum) {
    __shared__ int s[S1B];
    int tid = threadIdx.x;
    int i = blockIdx.x * S1B + tid;
    int v = (i < SCM) ? in[i] : 0;
    s[tid] = v;
    __syncthreads();
    #pragma unroll
    for (int o = 1; o < S1B; o <<= 1) {
        int t = (tid >= o) ? s[tid - o] : 0;
        __syncthreads();
        s[tid] += t;
        __syncthreads();
    }
    if (i < SCM) base[i] = s[tid] - v;
    if (tid == S1B - 1) bsum[blockIdx.x] = s[tid];
}

__global__ __launch_bounds__(64) void k_scanB(int* __restrict__ bsum) {
    int tid = threadIdx.x;                 // one wave, NSB=49 <= 64
    int v = (tid < NSB) ? bsum[tid] : 0;
    int x = v;
    #pragma unroll
    for (int o = 1; o < 64; o <<= 1) {
        int t = __shfl_up(x, o);
        if (tid >= o) x += t;
    }
    if (tid < NSB) bsum[tid] = x - v;      // exclusive
}

__global__ __launch_bounds__(S1B) void k_scanC(int* __restrict__ base,
                                               const int* __restrict__ bsum) {
    int i = blockIdx.x * S1B + threadIdx.x;
    if (i < SCM) base[i] += bsum[blockIdx.x];
}

// ---------------- Phase C: coarse scatter into bucket-sorted tmp ----------------
__global__ __launch_bounds__(CB_THREADS) void k_coarse(const int* __restrict__ rowi,
                                                       const int* __restrict__ coli,
                                                       const int* __restrict__ base,
                                                       int* __restrict__ tmp) {
    __shared__ int cur[NBKT];
    for (int i = threadIdx.x; i < NBKT; i += CB_THREADS)
        cur[i] = base[i * CB_BLOCKS + blockIdx.x];
    __syncthreads();
    const int e0 = blockIdx.x * EPB;
    const int e1 = min(e0 + EPB, E_EDGES);
    for (int e = e0 + (int)threadIdx.x; e < e1; e += CB_THREADS) {
        int c = coli[e];
        int pos = atomicAdd(&cur[c >> 7], 1);
        tmp[pos] = rowi[e] | ((c & 127) << 17);
    }
}

// ---------------- Phase D: fine counting-sort + off[] + dinv[] ----------------
__global__ __launch_bounds__(256) void k_fine(const int* __restrict__ tmp,
                                              const int* __restrict__ base,
                                              int* __restrict__ csr,
                                              int* __restrict__ off,
                                              float* __restrict__ dinv) {
    __shared__ int hist[NPB];
    __shared__ int scn[NPB];
    const int b = blockIdx.x;
    const int tid = threadIdx.x;
    const int bb = base[b * CB_BLOCKS];
    const int be = (b + 1 < NBKT) ? base[(b + 1) * CB_BLOCKS] : E_EDGES;
    if (tid < NPB) hist[tid] = 0;
    __syncthreads();
    for (int i = bb + tid; i < be; i += 256)
        atomicAdd(&hist[(tmp[i] >> 17) & 127], 1);
    __syncthreads();
    if (tid < NPB) scn[tid] = hist[tid];
    __syncthreads();
    #pragma unroll
    for (int o = 1; o < NPB; o <<= 1) {
        int t = (tid < NPB && tid >= o) ? scn[tid - o] : 0;
        __syncthreads();
        if (tid < NPB) scn[tid] += t;
        __syncthreads();
    }
    if (tid < NPB) {
        int node = b * NPB + tid;
        int excl = scn[tid] - hist[tid];
        if (node < N_NODES) {
            off[node] = bb + excl;
            dinv[node] = rsqrtf((float)(hist[tid] + 1));   // +1 self-loop
        }
        scn[tid] = bb + excl;
    }
    if (b == NBKT - 1 && tid == 0) off[N_NODES] = E_EDGES;
    __syncthreads();
    for (int i = bb + tid; i < be; i += 256) {
        int v = tmp[i];
        int pos = atomicAdd(&scn[(v >> 17) & 127], 1);
        csr[pos] = v & 0x1ffff;
    }
}

// ---------------- W pack: fp32 [128][128] -> bf16 B-fragments ----------------
// frag (t,s,lane): B[k = s*32 + (lane>>4)*8 + j][n = t*16 + (lane&15)], j=0..7
__global__ __launch_bounds__(256) void k_packW(const float* __restrict__ W,
                                               uint4* __restrict__ Wp) {
    int tid = blockIdx.x * 256 + threadIdx.x;   // 0..2047
    int L = tid & 63;
    int ts = tid >> 6;                           // 0..31
    int t = ts >> 2, s = ts & 3;
    int n = t * 16 + (L & 15);
    int k0 = s * 32 + (L >> 4) * 8;
    unsigned e[8];
    #pragma unroll
    for (int j = 0; j < 8; ++j) e[j] = f2bf(W[(k0 + j) * C + n]);
    uint4 v;
    v.x = e[0] | (e[1] << 16);
    v.y = e[2] | (e[3] << 16);
    v.z = e[4] | (e[5] << 16);
    v.w = e[6] | (e[7] << 16);
    Wp[tid] = v;
}

// ---------------- MFMA encoder GEMM [N,128]@[128,128] -> bf16, rows scaled by dinv ----------
// block 256 (4 waves), 64-row tile; wave w handles rows w*16..w*16+15;
// 8 col-tiles x 4 k-steps of 16x16x32 MFMA.
__global__ __launch_bounds__(256) void k_gemm_mfma(const float* __restrict__ X,
                                                   const uint4* __restrict__ Wp,
                                                   const float* __restrict__ dinv,
                                                   unsigned short* __restrict__ Hb) {
    __shared__ float xs[64][C];        // 32 KB, reused as bf16 out-staging
    __shared__ float sd[64];
    const int t = threadIdx.x;
    const int r0 = blockIdx.x * 64;
    const bool full = (r0 + 64 <= N_NODES);

    {   // stage 64x128 X tile (coalesced float4)
        const float4* X4 = (const float4*)(X + (size_t)r0 * C);
        float4* s4 = (float4*)xs;
        #pragma unroll
        for (int i = 0; i < 8; ++i) {
            int li = t + i * 256;
            if (full || (r0 + (li >> 5) < N_NODES)) s4[li] = X4[li];
            else s4[li] = make_float4(0.f, 0.f, 0.f, 0.f);
        }
        if (t < 64) sd[t] = (r0 + t < N_NODES) ? dinv[r0 + t] : 1.f;
    }
    __syncthreads();

    const int w = t >> 6;              // wave 0..3
    const int lane = t & 63;
    const int m = lane & 15;
    const int q = lane >> 4;
    const int arow = w * 16 + m;       // A row this lane reads

    f32x4 acc[8];
    #pragma unroll
    for (int i = 0; i < 8; ++i) acc[i] = (f32x4){0.f, 0.f, 0.f, 0.f};

    const bf16x8* Wp8 = (const bf16x8*)Wp;
    #pragma unroll
    for (int s = 0; s < 4; ++s) {
        const int k0 = s * 32 + q * 8;
        float4 va = *(const float4*)&xs[arow][k0];
        float4 vb = *(const float4*)&xs[arow][k0 + 4];
        bf16x8 a;
        a[0] = (short)f2bf(va.x); a[1] = (short)f2bf(va.y);
        a[2] = (short)f2bf(va.z); a[3] = (short)f2bf(va.w);
        a[4] = (short)f2bf(vb.x); a[5] = (short)f2bf(vb.y);
        a[6] = (short)f2bf(vb.z); a[7] = (short)f2bf(vb.w);
        #pragma unroll
        for (int tt = 0; tt < 8; ++tt) {
            bf16x8 b = Wp8[(tt * 4 + s) * 64 + lane];
            acc[tt] = __builtin_amdgcn_mfma_f32_16x16x32_bf16(a, b, acc[tt], 0, 0, 0);
        }
    }

    __syncthreads();                   // all waves done reading xs
    unsigned short* hb = (unsigned short*)xs;   // 64x128 bf16 staging
    const int lrb = w * 16 + q * 4;
    #pragma unroll
    for (int r = 0; r < 4; ++r) {
        float sc = sd[lrb + r];
        #pragma unroll
        for (int tt = 0; tt < 8; ++tt)
            hb[(lrb + r) * C + tt * 16 + m] = f2bf(acc[tt][r] * sc);
    }
    __syncthreads();

    // coalesced store: 64x128 bf16 = 1024 uint4
    const uint4* src = (const uint4*)hb;
    uint4* dst = (uint4*)(Hb + (size_t)r0 * C);
    #pragma unroll
    for (int i = 0; i < 4; ++i) {
        int li = t + i * 256;
        if (full || (r0 + (li >> 4) < N_NODES)) dst[li] = src[li];
    }
}

// ---------------- fused aggregation over bf16 scaled rows ----------------
// 16 lanes per node (4 nodes per wave). Lane sl owns channels sl*8..sl*8+7
// for its node: per-node fixed overhead (off/dinv/bias/scale/store) is paid
// by 16-lane groups — 4 nodes per wave-instruction — and the cross-slot
// combine vanishes. Adjacency indices are chunk-preloaded (16/lane-group)
// with group-local __shfl broadcast; gathers run 4-deep per group (16 rows
// in flight per wave). Tail slots redirect to the zeroed ZROW row (1 cndmask
// instead of 4-op register zeroing).
#define ACC8(v)                                                             \
    do {                                                                    \
        f32x2 t0 = {__uint_as_float((v).x << 16),                           \
                    __uint_as_float((v).x & 0xffff0000u)};                  \
        f32x2 t1 = {__uint_as_float((v).y << 16),                           \
                    __uint_as_float((v).y & 0xffff0000u)};                  \
        f32x2 t2 = {__uint_as_float((v).z << 16),                           \
                    __uint_as_float((v).z & 0xffff0000u)};                  \
        f32x2 t3 = {__uint_as_float((v).w << 16),                           \
                    __uint_as_float((v).w & 0xffff0000u)};                  \
        acc2[0] += t0;                                                      \
        acc2[1] += t1;                                                      \
        acc2[2] += t2;                                                      \
        acc2[3] += t3;                                                      \
    } while (0)

template <bool RELU>
__global__ __launch_bounds__(256) void k_aggregate(const uint4* __restrict__ Hb4,
                                                   const int* __restrict__ csr,
                                                   const int* __restrict__ off,
                                                   const float* __restrict__ dinv,
                                                   const float* __restrict__ bias,
                                                   float* __restrict__ A,
                                                   float* __restrict__ invn) {
    const int tid = threadIdx.x;
    const int gid = (blockIdx.x * 256 + tid) >> 4;   // node (16 lanes/node)
    if (gid >= N_NODES) return;                      // grid exact: never taken
    const int sl = tid & 15;                         // 16B chunk of 256B row
    const int grpbase = (tid & 63) & 48;             // group base lane in wave
    const unsigned sl16 = (unsigned)sl << 4;
    const char* Hbb = (const char*)Hb4;
    const int s0 = off[gid];
    const int e1 = off[gid + 1];
    const int deg = e1 - s0;
    const float di = dinv[gid];

    f32x2 acc2[4];
    #pragma unroll
    for (int j = 0; j < 4; ++j) acc2[j] = (f32x2){0.f, 0.f};

    // self row (already dinv[gid]-scaled)
    {
        uint4 v = *(const uint4*)(Hbb + (((unsigned)gid << 8) + sl16));
        ACC8(v);
    }

    // chunk-preload of adjacency indices: lane sl holds csr[s0 + chunk + sl]
    int myidx = csr[min(s0 + sl, E_EDGES - 1)];
    for (int base = 0; base < deg; base += 16) {
        if (base) myidx = csr[min(s0 + base + sl, E_EDGES - 1)];
        for (int q = 0; q < 16 && base + q < deg; q += 4) {
            const int p1 = base + q + 1, p2 = base + q + 2, p3 = base + q + 3;
            int i0 = __shfl(myidx, grpbase + q + 0);           // p0 < deg by loop cond
            int i1 = (p1 < deg) ? __shfl(myidx, grpbase + q + 1) : ZROW;
            int i2 = (p2 < deg) ? __shfl(myidx, grpbase + q + 2) : ZROW;
            int i3 = (p3 < deg) ? __shfl(myidx, grpbase + q + 3) : ZROW;
            uint4 v0 = *(const uint4*)(Hbb + (((unsigned)i0 << 8) + sl16));
            uint4 v1 = *(const uint4*)(Hbb + (((unsigned)i1 << 8) + sl16));
            uint4 v2 = *(const uint4*)(Hbb + (((unsigned)i2 << 8) + sl16));
            uint4 v3 = *(const uint4*)(Hbb + (((unsigned)i3 << 8) + sl16));
            ACC8(v0);
            ACC8(v1);
            ACC8(v2);
            ACC8(v3);
        }
    }

    float4 b0 = ((const float4*)bias)[sl * 2];
    float4 b1 = ((const float4*)bias)[sl * 2 + 1];
    acc2[0] = acc2[0] * di + (f32x2){b0.x, b0.y};
    acc2[1] = acc2[1] * di + (f32x2){b0.z, b0.w};
    acc2[2] = acc2[2] * di + (f32x2){b1.x, b1.y};
    acc2[3] = acc2[3] * di + (f32x2){b1.z, b1.w};

    if (RELU) {
        #pragma unroll
        for (int j = 0; j < 4; ++j) {
            acc2[j].x = fmaxf(acc2[j].x, 0.f);
            acc2[j].y = fmaxf(acc2[j].y, 0.f);
        }
    } else {
        float ss = 0.f;
        #pragma unroll
        for (int j = 0; j < 4; ++j) ss += acc2[j].x * acc2[j].x + acc2[j].y * acc2[j].y;
        // reduce over the 16 lanes of this group (xor 1,2,4,8 stays in-group)
        #pragma unroll
        for (int o = 1; o < 16; o <<= 1) ss += __shfl_xor(ss, o);
        if (sl == 0) invn[gid] = 1.f / (sqrtf(ss) + 1e-12f);
    }

    // store: lane sl writes channels sl*8..sl*8+7 (two float4)
    float4* dst = (float4*)(A + (size_t)gid * C + sl * 8);
    dst[0] = make_float4(acc2[0].x, acc2[0].y, acc2[1].x, acc2[1].y);
    dst[1] = make_float4(acc2[2].x, acc2[2].y, acc2[3].x, acc2[3].y);
}

// ---------------- fused decode: G = X@Wd, logp = log_softmax(G*invn + bd), emb = X*invn ----------
__global__ __launch_bounds__(256) void k_decode(const float* __restrict__ X,
                                                const float* __restrict__ Wd,
                                                const float* __restrict__ bd,
                                                const float* __restrict__ invn,
                                                float* __restrict__ out_logp,
                                                float* __restrict__ out_emb) {
    __shared__ float xs[64][C];        // 32 KB
    __shared__ float sInv[64];
    const int t = threadIdx.x;
    const int r0 = blockIdx.x * 64;

    {
        const float4* X4 = (const float4*)(X + (size_t)r0 * C);
        float4* s4 = (float4*)xs;
        const bool full = (r0 + 64 <= N_NODES);
        #pragma unroll
        for (int i = 0; i < 8; ++i) {
            int li = t + i * 256;
            if (full || (r0 + (li >> 5) < N_NODES)) s4[li] = X4[li];
            else s4[li] = make_float4(0.f, 0.f, 0.f, 0.f);
        }
        if (t < 64) sInv[t] = (r0 + t < N_NODES) ? invn[r0 + t] : 1.f;
    }
    __syncthreads();

    const int tx = t % 16;             // col group (4 cols of 64)
    const int ty = t / 16;             // row group (4 rows)
    float acc[4][4];
    #pragma unroll
    for (int r = 0; r < 4; ++r)
        #pragma unroll
        for (int c = 0; c < 4; ++c) acc[r][c] = 0.f;

    for (int k = 0; k < C; k += 4) {
        float4 w[4];
        #pragma unroll
        for (int kk = 0; kk < 4; ++kk)
            w[kk] = *(const float4*)&Wd[(k + kk) * OUTC + 4 * tx];
        float4 xr[4];
        #pragma unroll
        for (int r = 0; r < 4; ++r)
            xr[r] = *(const float4*)&xs[ty * 4 + r][k];
        #pragma unroll
        for (int r = 0; r < 4; ++r) {
            #pragma unroll
            for (int c = 0; c < 4; ++c) {
                acc[r][c] += xr[r].x * ((const float*)&w[0])[c]
                           + xr[r].y * ((const float*)&w[1])[c]
                           + xr[r].z * ((const float*)&w[2])[c]
                           + xr[r].w * ((const float*)&w[3])[c];
            }
        }
    }

    float4 bdv = *(const float4*)&bd[4 * tx];
    #pragma unroll
    for (int r = 0; r < 4; ++r) {
        int lrow = ty * 4 + r;
        float inv = sInv[lrow];
        float g0 = acc[r][0] * inv + bdv.x;
        float g1 = acc[r][1] * inv + bdv.y;
        float g2 = acc[r][2] * inv + bdv.z;
        float g3 = acc[r][3] * inv + bdv.w;
        float m = fmaxf(fmaxf(g0, g1), fmaxf(g2, g3));
        #pragma unroll
        for (int o = 1; o < 16; o <<= 1) m = fmaxf(m, __shfl_xor(m, o, 16));
        float s = expf(g0 - m) + expf(g1 - m) + expf(g2 - m) + expf(g3 - m);
        #pragma unroll
        for (int o = 1; o < 16; o <<= 1) s += __shfl_xor(s, o, 16);
        float ls = m + logf(s);
        int row = r0 + lrow;
        if (row < N_NODES) {
            float4 v = make_float4(g0 - ls, g1 - ls, g2 - ls, g3 - ls);
            *(float4*)&out_logp[(size_t)row * OUTC + 4 * tx] = v;
        }
    }

    const bool full = (r0 + 64 <= N_NODES);
    const float4* s4 = (const float4*)xs;
    #pragma unroll
    for (int i = 0; i < 8; ++i) {
        int li = t + i * 256;
        int lrow = li >> 5;
        if (full || (r0 + lrow < N_NODES)) {
            float inv = sInv[lrow];
            float4 v = s4[li];
            v.x *= inv; v.y *= inv; v.z *= inv; v.w *= inv;
            *(float4*)&out_emb[(size_t)r0 * C + 4 * li] = v;
        }
    }
}

extern "C" void kernel_launch(void* const* d_in, const int* in_sizes, int n_in,
                              void* d_out, int out_size, void* d_ws, size_t ws_size,
                              hipStream_t stream) {
    const float* x  = (const float*)d_in[0];
    const int*   ei = (const int*)d_in[1];
    const int* rowi = ei;
    const int* coli = ei + E_EDGES;
    const float* W1 = (const float*)d_in[2];
    const float* b1 = (const float*)d_in[3];
    const float* W2 = (const float*)d_in[4];
    const float* b2 = (const float*)d_in[5];
    const float* Wd = (const float*)d_in[6];
    const float* bd = (const float*)d_in[7];

    float* out_logp = (float*)d_out;                             // [N,64]
    float* out_emb  = (float*)d_out + (long long)N_NODES * OUTC; // [N,128]

    // workspace layout (16B-aligned regions)
    char* p = (char*)d_ws;
    float* dinv = (float*)p;                  p += sizeof(float) * N_NODES;
    unsigned short* Hb = (unsigned short*)p;  p += sizeof(short) * (size_t)(N_NODES + 4) * C; // +4 rows (ZROW pad)
    float* agg   = (float*)p;                 p += sizeof(float) * (size_t)N_NODES * C;
    int*   off   = (int*)p;                   p += sizeof(int) * (N_NODES + 4);
    int*   histG = (int*)p;                   p += sizeof(int) * SCM;
    int*   base  = (int*)p;                   p += sizeof(int) * SCM;
    int*   bsum  = (int*)p;                   p += sizeof(int) * 64;
    int*   tmp   = (int*)p;                   p += sizeof(int) * (size_t)E_EDGES;
    int*   csr   = (int*)p;                   p += sizeof(int) * (size_t)E_EDGES;
    float* invn  = (float*)p;                 p += sizeof(float) * N_NODES;
    uint4* Wp1   = (uint4*)p;                 p += sizeof(uint4) * 2048;
    uint4* Wp2   = (uint4*)p;                 p += sizeof(uint4) * 2048;

    // --- CSR build (also produces off[] and dinv[]) + W packs + ZROW ---
    k_zrow<<<1, 64, 0, stream>>>((uint4*)Hb);
    k_hist<<<CB_BLOCKS, CB_THREADS, 0, stream>>>(coli, histG);
    k_packW<<<8, 256, 0, stream>>>(W1, Wp1);
    k_packW<<<8, 256, 0, stream>>>(W2, Wp2);
    k_scanA<<<NSB, S1B, 0, stream>>>(histG, base, bsum);
    k_scanB<<<1, 64, 0, stream>>>(bsum);
    k_scanC<<<NSB, S1B, 0, stream>>>(base, bsum);
    k_coarse<<<CB_BLOCKS, CB_THREADS, 0, stream>>>(rowi, coli, base, tmp);
    k_fine<<<NBKT, 256, 0, stream>>>(tmp, base, csr, off, dinv);

    const int GB = (N_NODES + 63) / 64;   // 1563
    const int AB = (N_NODES * 16 + 255) / 256;   // 6250 (16 lanes per node)
    // --- conv1 ---
    k_gemm_mfma<<<GB, 256, 0, stream>>>(x, Wp1, dinv, Hb);
    k_aggregate<true><<<AB, 256, 0, stream>>>((const uint4*)Hb, csr, off, dinv, b1, agg, nullptr);
    // --- conv2 ---
    k_gemm_mfma<<<GB, 256, 0, stream>>>(agg, Wp2, dinv, Hb);
    k_aggregate<false><<<AB, 256, 0, stream>>>((const uint4*)Hb, csr, off, dinv, b2, agg, invn);
    // --- fused decode ---
    k_decode<<<GB, 256, 0, stream>>>(agg, Wd, bd, invn, out_logp, out_emb);
}

// Round 6
// 397.666 us; speedup vs baseline: 1.0495x; 1.0495x over previous
//
#include <hip/hip_runtime.h>

#define N_NODES 100000
#define E_EDGES 1600000
#define C 128     // IN_C = H1 = H2
#define OUTC 64
#define ZROW N_NODES   // index of the dedicated all-zero Hb row

// ---- CSR build (two-level counting sort) constants ----
#define NPB 128                                   // nodes per bucket (dest >> 7)
#define NBKT ((N_NODES + NPB - 1) / NPB)          // 782 buckets
#define CB_BLOCKS 64                              // phase A/C blocks
#define CB_THREADS 1024
#define EPB ((E_EDGES + CB_BLOCKS - 1) / CB_BLOCKS)  // 25000 edges/block
#define SCM (NBKT * CB_BLOCKS)                    // 50048 scan elements
#define S1B 1024
#define NSB ((SCM + S1B - 1) / S1B)               // 49

typedef __attribute__((ext_vector_type(8))) short bf16x8;
typedef __attribute__((ext_vector_type(4))) float f32x4;
typedef __attribute__((ext_vector_type(2))) float f32x2;

// rne float->bf16
__device__ inline unsigned short f2bf(float x) {
    unsigned u = __float_as_uint(x);
    unsigned r = u + 0x7fffu + ((u >> 16) & 1u);
    return (unsigned short)(r >> 16);
}

// ---------------- Phase A: per-block bucket histogram ----------------
__global__ __launch_bounds__(CB_THREADS) void k_hist(const int* __restrict__ coli,
                                                     int* __restrict__ histG) {
    __shared__ int h[NBKT];
    for (int i = threadIdx.x; i < NBKT; i += CB_THREADS) h[i] = 0;
    __syncthreads();
    const int e0 = blockIdx.x * EPB;
    const int e1 = min(e0 + EPB, E_EDGES);
    for (int e = e0 + (int)threadIdx.x; e < e1; e += CB_THREADS)
        atomicAdd(&h[coli[e] >> 7], 1);
    __syncthreads();
    for (int i = threadIdx.x; i < NBKT; i += CB_THREADS)
        histG[i * CB_BLOCKS + blockIdx.x] = h[i];      // bucket-major
}

// ---------------- Phase B: exclusive scan of histG[SCM] ----------------
__global__ __launch_bounds__(S1B) void k_scanA(const int* __restrict__ in,
                                               int* __restrict__ base,
                                               int* __restrict__ bsum) {
    __shared__ int s[S1B];
    int tid = threadIdx.x;
    int i = blockIdx.x * S1B + tid;
    int v = (i < SCM) ? in[i] : 0;
    s[tid] = v;
    __syncthreads();
    #pragma unroll
    for (int o = 1; o < S1B; o <<= 1) {
        int t = (tid >= o) ? s[tid - o] : 0;
        __syncthreads();
        s[tid] += t;
        __syncthreads();
    }
    if (i < SCM) base[i] = s[tid] - v;
    if (tid == S1B - 1) bsum[blockIdx.x] = s[tid];
}

__global__ __launch_bounds__(64) void k_scanB(int* __restrict__ bsum) {
    int tid = threadIdx.x;                 // one wave, NSB=49 <= 64
    int v = (tid < NSB) ? bsum[tid] : 0;
    int x = v;
    #pragma unroll
    for (int o = 1; o < 64; o <<= 1) {
        int t = __shfl_up(x, o);
        if (tid >= o) x += t;
    }
    if (tid < NSB) bsum[tid] = x - v;      // exclusive
}

__global__ __launch_bounds__(S1B) void k_scanC(int* __restrict__ base,
                                               const int* __restrict__ bsum) {
    int i = blockIdx.x * S1B + threadIdx.x;
    if (i < SCM) base[i] += bsum[blockIdx.x];
}

// ---------------- Phase C: coarse scatter into bucket-sorted tmp ----------------
__global__ __launch_bounds__(CB_THREADS) void k_coarse(const int* __restrict__ rowi,
                                                       const int* __restrict__ coli,
                                                       const int* __restrict__ base,
                                                       int* __restrict__ tmp) {
    __shared__ int cur[NBKT];
    for (int i = threadIdx.x; i < NBKT; i += CB_THREADS)
        cur[i] = base[i * CB_BLOCKS + blockIdx.x];
    __syncthreads();
    const int e0 = blockIdx.x * EPB;
    const int e1 = min(e0 + EPB, E_EDGES);
    for (int e = e0 + (int)threadIdx.x; e < e1; e += CB_THREADS) {
        int c = coli[e];
        int pos = atomicAdd(&cur[c >> 7], 1);
        tmp[pos] = rowi[e] | ((c & 127) << 17);
    }
}

// ---------------- Phase D: fine counting-sort + off[] + dinv[] ----------------
__global__ __launch_bounds__(256) void k_fine(const int* __restrict__ tmp,
                                              const int* __restrict__ base,
                                              int* __restrict__ csr,
                                              int* __restrict__ off,
                                              float* __restrict__ dinv) {
    __shared__ int hist[NPB];
    __shared__ int scn[NPB];
    const int b = blockIdx.x;
    const int tid = threadIdx.x;
    const int bb = base[b * CB_BLOCKS];
    const int be = (b + 1 < NBKT) ? base[(b + 1) * CB_BLOCKS] : E_EDGES;
    if (tid < NPB) hist[tid] = 0;
    __syncthreads();
    for (int i = bb + tid; i < be; i += 256)
        atomicAdd(&hist[(tmp[i] >> 17) & 127], 1);
    __syncthreads();
    if (tid < NPB) scn[tid] = hist[tid];
    __syncthreads();
    #pragma unroll
    for (int o = 1; o < NPB; o <<= 1) {
        int t = (tid < NPB && tid >= o) ? scn[tid - o] : 0;
        __syncthreads();
        if (tid < NPB) scn[tid] += t;
        __syncthreads();
    }
    if (tid < NPB) {
        int node = b * NPB + tid;
        int excl = scn[tid] - hist[tid];
        if (node < N_NODES) {
            off[node] = bb + excl;
            dinv[node] = rsqrtf((float)(hist[tid] + 1));   // +1 self-loop
        }
        scn[tid] = bb + excl;
    }
    if (b == NBKT - 1 && tid == 0) off[N_NODES] = E_EDGES;
    __syncthreads();
    for (int i = bb + tid; i < be; i += 256) {
        int v = tmp[i];
        int pos = atomicAdd(&scn[(v >> 17) & 127], 1);
        csr[pos] = v & 0x1ffff;
    }
}

// ---------------- W pack: fp32 [128][128] -> bf16 B-fragments ----------------
// frag (t,s,lane): B[k = s*32 + (lane>>4)*8 + j][n = t*16 + (lane&15)], j=0..7
// Block 8 (when launched with 9 blocks) zeroes the dedicated ZROW of Hb.
__global__ __launch_bounds__(256) void k_packW(const float* __restrict__ W,
                                               uint4* __restrict__ Wp,
                                               uint4* __restrict__ Hbz) {
    if (blockIdx.x == 8) {
        if (threadIdx.x < 16)
            Hbz[(size_t)ZROW * 16 + threadIdx.x] = make_uint4(0u, 0u, 0u, 0u);
        return;
    }
    int tid = blockIdx.x * 256 + threadIdx.x;   // 0..2047
    int L = tid & 63;
    int ts = tid >> 6;                           // 0..31
    int t = ts >> 2, s = ts & 3;
    int n = t * 16 + (L & 15);
    int k0 = s * 32 + (L >> 4) * 8;
    unsigned e[8];
    #pragma unroll
    for (int j = 0; j < 8; ++j) e[j] = f2bf(W[(k0 + j) * C + n]);
    uint4 v;
    v.x = e[0] | (e[1] << 16);
    v.y = e[2] | (e[3] << 16);
    v.z = e[4] | (e[5] << 16);
    v.w = e[6] | (e[7] << 16);
    Wp[tid] = v;
}

// ---------------- MFMA encoder GEMM [N,128]@[128,128] -> bf16, rows scaled by dinv ----------
// block 256 (4 waves), 64-row tile; wave w handles rows w*16..w*16+15;
// 8 col-tiles x 4 k-steps of 16x16x32 MFMA.
// BF16IN: A-matrix is bf16 [N,128] (written by k_aggregate<true>); staging is
// 16KB of uint4 and fragments read directly (no f2bf on the critical path).
template <bool BF16IN>
__global__ __launch_bounds__(256) void k_gemm_mfma(const void* __restrict__ Xv,
                                                   const uint4* __restrict__ Wp,
                                                   const float* __restrict__ dinv,
                                                   unsigned short* __restrict__ Hb) {
    __shared__ float xs[64][C];        // 32 KB, reused as bf16 out-staging
    __shared__ float sd[64];
    const int t = threadIdx.x;
    const int r0 = blockIdx.x * 64;
    const bool full = (r0 + 64 <= N_NODES);

    if (BF16IN) {   // stage 64x128 bf16 tile (coalesced uint4: 1024 x 16B/4)
        const uint4* X4 = (const uint4*)((const unsigned short*)Xv + (size_t)r0 * C);
        uint4* s4 = (uint4*)xs;        // first 16KB
        #pragma unroll
        for (int i = 0; i < 4; ++i) {
            int li = t + i * 256;      // 0..1023, row = li>>4
            if (full || (r0 + (li >> 4) < N_NODES)) s4[li] = X4[li];
            else s4[li] = make_uint4(0u, 0u, 0u, 0u);
        }
    } else {        // stage 64x128 fp32 tile (coalesced float4)
        const float4* X4 = (const float4*)((const float*)Xv + (size_t)r0 * C);
        float4* s4 = (float4*)xs;
        #pragma unroll
        for (int i = 0; i < 8; ++i) {
            int li = t + i * 256;
            if (full || (r0 + (li >> 5) < N_NODES)) s4[li] = X4[li];
            else s4[li] = make_float4(0.f, 0.f, 0.f, 0.f);
        }
    }
    if (t < 64) sd[t] = (r0 + t < N_NODES) ? dinv[r0 + t] : 1.f;
    __syncthreads();

    const int w = t >> 6;              // wave 0..3
    const int lane = t & 63;
    const int m = lane & 15;
    const int q = lane >> 4;
    const int arow = w * 16 + m;       // A row this lane reads

    f32x4 acc[8];
    #pragma unroll
    for (int i = 0; i < 8; ++i) acc[i] = (f32x4){0.f, 0.f, 0.f, 0.f};

    const bf16x8* Wp8 = (const bf16x8*)Wp;
    const unsigned short* xb = (const unsigned short*)xs;
    #pragma unroll
    for (int s = 0; s < 4; ++s) {
        const int k0 = s * 32 + q * 8;
        bf16x8 a;
        if (BF16IN) {
            a = *(const bf16x8*)&xb[arow * C + k0];
        } else {
            float4 va = *(const float4*)&xs[arow][k0];
            float4 vb = *(const float4*)&xs[arow][k0 + 4];
            a[0] = (short)f2bf(va.x); a[1] = (short)f2bf(va.y);
            a[2] = (short)f2bf(va.z); a[3] = (short)f2bf(va.w);
            a[4] = (short)f2bf(vb.x); a[5] = (short)f2bf(vb.y);
            a[6] = (short)f2bf(vb.z); a[7] = (short)f2bf(vb.w);
        }
        #pragma unroll
        for (int tt = 0; tt < 8; ++tt) {
            bf16x8 b = Wp8[(tt * 4 + s) * 64 + lane];
            acc[tt] = __builtin_amdgcn_mfma_f32_16x16x32_bf16(a, b, acc[tt], 0, 0, 0);
        }
    }

    __syncthreads();                   // all waves done reading xs
    unsigned short* hb = (unsigned short*)xs;   // 64x128 bf16 staging
    const int lrb = w * 16 + q * 4;
    #pragma unroll
    for (int r = 0; r < 4; ++r) {
        float sc = sd[lrb + r];
        #pragma unroll
        for (int tt = 0; tt < 8; ++tt)
            hb[(lrb + r) * C + tt * 16 + m] = f2bf(acc[tt][r] * sc);
    }
    __syncthreads();

    // coalesced store: 64x128 bf16 = 1024 uint4
    const uint4* src = (const uint4*)hb;
    uint4* dst = (uint4*)(Hb + (size_t)r0 * C);
    #pragma unroll
    for (int i = 0; i < 4; ++i) {
        int li = t + i * 256;
        if (full || (r0 + (li >> 4) < N_NODES)) dst[li] = src[li];
    }
}

// ---------------- fused aggregation over bf16 scaled rows ----------------
// 16 lanes per node (4 nodes per wave). Lane sl owns channels sl*8..sl*8+7.
// Layer 1 (RELU=true): out = bf16 [N,128] (rounded with the same f2bf the
// GEMM would apply — bit-identical downstream, half the write+read bytes).
// Layer 2 (RELU=false): out = fp32 normalized embeddings written DIRECTLY
// to out_emb (h * rsqrt(||h||^2)); no agg round-trip, no invn array.
#define ACC8(v)                                                             \
    do {                                                                    \
        f32x2 t0 = {__uint_as_float((v).x << 16),                           \
                    __uint_as_float((v).x & 0xffff0000u)};                  \
        f32x2 t1 = {__uint_as_float((v).y << 16),                           \
                    __uint_as_float((v).y & 0xffff0000u)};                  \
        f32x2 t2 = {__uint_as_float((v).z << 16),                           \
                    __uint_as_float((v).z & 0xffff0000u)};                  \
        f32x2 t3 = {__uint_as_float((v).w << 16),                           \
                    __uint_as_float((v).w & 0xffff0000u)};                  \
        acc2[0] += t0;                                                      \
        acc2[1] += t1;                                                      \
        acc2[2] += t2;                                                      \
        acc2[3] += t3;                                                      \
    } while (0)

template <bool RELU>
__global__ __launch_bounds__(256) void k_aggregate(const uint4* __restrict__ Hb4,
                                                   const int* __restrict__ csr,
                                                   const int* __restrict__ off,
                                                   const float* __restrict__ dinv,
                                                   const float* __restrict__ bias,
                                                   void* __restrict__ Aout) {
    const int tid = threadIdx.x;
    const int gid = (blockIdx.x * 256 + tid) >> 4;   // node (16 lanes/node)
    if (gid >= N_NODES) return;                      // grid exact: never taken
    const int sl = tid & 15;                         // 16B chunk of 256B row
    const int grpbase = (tid & 63) & 48;             // group base lane in wave
    const unsigned sl16 = (unsigned)sl << 4;
    const char* Hbb = (const char*)Hb4;
    const int s0 = off[gid];
    const int e1 = off[gid + 1];
    const int deg = e1 - s0;
    const float di = dinv[gid];

    f32x2 acc2[4];
    #pragma unroll
    for (int j = 0; j < 4; ++j) acc2[j] = (f32x2){0.f, 0.f};

    // self row (already dinv[gid]-scaled)
    {
        uint4 v = *(const uint4*)(Hbb + (((unsigned)gid << 8) + sl16));
        ACC8(v);
    }

    // chunk-preload of adjacency indices: lane sl holds csr[s0 + chunk + sl]
    int myidx = csr[min(s0 + sl, E_EDGES - 1)];
    for (int base = 0; base < deg; base += 16) {
        if (base) myidx = csr[min(s0 + base + sl, E_EDGES - 1)];
        for (int q = 0; q < 16 && base + q < deg; q += 4) {
            const int p1 = base + q + 1, p2 = base + q + 2, p3 = base + q + 3;
            int i0 = __shfl(myidx, grpbase + q + 0);           // p0 < deg by loop cond
            int i1 = (p1 < deg) ? __shfl(myidx, grpbase + q + 1) : ZROW;
            int i2 = (p2 < deg) ? __shfl(myidx, grpbase + q + 2) : ZROW;
            int i3 = (p3 < deg) ? __shfl(myidx, grpbase + q + 3) : ZROW;
            uint4 v0 = *(const uint4*)(Hbb + (((unsigned)i0 << 8) + sl16));
            uint4 v1 = *(const uint4*)(Hbb + (((unsigned)i1 << 8) + sl16));
            uint4 v2 = *(const uint4*)(Hbb + (((unsigned)i2 << 8) + sl16));
            uint4 v3 = *(const uint4*)(Hbb + (((unsigned)i3 << 8) + sl16));
            ACC8(v0);
            ACC8(v1);
            ACC8(v2);
            ACC8(v3);
        }
    }

    float4 b0 = ((const float4*)bias)[sl * 2];
    float4 b1 = ((const float4*)bias)[sl * 2 + 1];
    acc2[0] = acc2[0] * di + (f32x2){b0.x, b0.y};
    acc2[1] = acc2[1] * di + (f32x2){b0.z, b0.w};
    acc2[2] = acc2[2] * di + (f32x2){b1.x, b1.y};
    acc2[3] = acc2[3] * di + (f32x2){b1.z, b1.w};

    if (RELU) {
        #pragma unroll
        for (int j = 0; j < 4; ++j) {
            acc2[j].x = fmaxf(acc2[j].x, 0.f);
            acc2[j].y = fmaxf(acc2[j].y, 0.f);
        }
        // pack 8 channels to bf16 and store 16B (row = 256B by 16 lanes)
        uint4 o;
        o.x = (unsigned)f2bf(acc2[0].x) | ((unsigned)f2bf(acc2[0].y) << 16);
        o.y = (unsigned)f2bf(acc2[1].x) | ((unsigned)f2bf(acc2[1].y) << 16);
        o.z = (unsigned)f2bf(acc2[2].x) | ((unsigned)f2bf(acc2[2].y) << 16);
        o.w = (unsigned)f2bf(acc2[3].x) | ((unsigned)f2bf(acc2[3].y) << 16);
        ((uint4*)Aout)[(size_t)gid * 16 + sl] = o;
    } else {
        float ss = 0.f;
        #pragma unroll
        for (int j = 0; j < 4; ++j) ss += acc2[j].x * acc2[j].x + acc2[j].y * acc2[j].y;
        // reduce over the 16 lanes of this group (xor 1,2,4,8 stays in-group)
        #pragma unroll
        for (int o = 1; o < 16; o <<= 1) ss += __shfl_xor(ss, o);
        const float inv = 1.f / (sqrtf(ss) + 1e-12f);
        // store normalized embedding: lane sl writes channels sl*8..sl*8+7
        float4* dst = (float4*)((float*)Aout + (size_t)gid * C + sl * 8);
        dst[0] = make_float4(acc2[0].x * inv, acc2[0].y * inv,
                             acc2[1].x * inv, acc2[1].y * inv);
        dst[1] = make_float4(acc2[2].x * inv, acc2[2].y * inv,
                             acc2[3].x * inv, acc2[3].y * inv);
    }
}

// ---------------- decode: logp = log_softmax(E@Wd + bd), E = normalized emb ----------
__global__ __launch_bounds__(256) void k_decode(const float* __restrict__ E,
                                                const float* __restrict__ Wd,
                                                const float* __restrict__ bd,
                                                float* __restrict__ out_logp) {
    __shared__ float xs[64][C];        // 32 KB
    const int t = threadIdx.x;
    const int r0 = blockIdx.x * 64;

    {
        const float4* X4 = (const float4*)(E + (size_t)r0 * C);
        float4* s4 = (float4*)xs;
        const bool full = (r0 + 64 <= N_NODES);
        #pragma unroll
        for (int i = 0; i < 8; ++i) {
            int li = t + i * 256;
            if (full || (r0 + (li >> 5) < N_NODES)) s4[li] = X4[li];
            else s4[li] = make_float4(0.f, 0.f, 0.f, 0.f);
        }
    }
    __syncthreads();

    const int tx = t % 16;             // col group (4 cols of 64)
    const int ty = t / 16;             // row group (4 rows)
    float acc[4][4];
    #pragma unroll
    for (int r = 0; r < 4; ++r)
        #pragma unroll
        for (int c = 0; c < 4; ++c) acc[r][c] = 0.f;

    for (int k = 0; k < C; k += 4) {
        float4 w[4];
        #pragma unroll
        for (int kk = 0; kk < 4; ++kk)
            w[kk] = *(const float4*)&Wd[(k + kk) * OUTC + 4 * tx];
        float4 xr[4];
        #pragma unroll
        for (int r = 0; r < 4; ++r)
            xr[r] = *(const float4*)&xs[ty * 4 + r][k];
        #pragma unroll
        for (int r = 0; r < 4; ++r) {
            #pragma unroll
            for (int c = 0; c < 4; ++c) {
                acc[r][c] += xr[r].x * ((const float*)&w[0])[c]
                           + xr[r].y * ((const float*)&w[1])[c]
                           + xr[r].z * ((const float*)&w[2])[c]
                           + xr[r].w * ((const float*)&w[3])[c];
            }
        }
    }

    float4 bdv = *(const float4*)&bd[4 * tx];
    #pragma unroll
    for (int r = 0; r < 4; ++r) {
        int lrow = ty * 4 + r;
        float g0 = acc[r][0] + bdv.x;
        float g1 = acc[r][1] + bdv.y;
        float g2 = acc[r][2] + bdv.z;
        float g3 = acc[r][3] + bdv.w;
        float m = fmaxf(fmaxf(g0, g1), fmaxf(g2, g3));
        #pragma unroll
        for (int o = 1; o < 16; o <<= 1) m = fmaxf(m, __shfl_xor(m, o, 16));
        float s = expf(g0 - m) + expf(g1 - m) + expf(g2 - m) + expf(g3 - m);
        #pragma unroll
        for (int o = 1; o < 16; o <<= 1) s += __shfl_xor(s, o, 16);
        float ls = m + logf(s);
        int row = r0 + lrow;
        if (row < N_NODES) {
            float4 v = make_float4(g0 - ls, g1 - ls, g2 - ls, g3 - ls);
            *(float4*)&out_logp[(size_t)row * OUTC + 4 * tx] = v;
        }
    }
}

extern "C" void kernel_launch(void* const* d_in, const int* in_sizes, int n_in,
                              void* d_out, int out_size, void* d_ws, size_t ws_size,
                              hipStream_t stream) {
    const float* x  = (const float*)d_in[0];
    const int*   ei = (const int*)d_in[1];
    const int* rowi = ei;
    const int* coli = ei + E_EDGES;
    const float* W1 = (const float*)d_in[2];
    const float* b1 = (const float*)d_in[3];
    const float* W2 = (const float*)d_in[4];
    const float* b2 = (const float*)d_in[5];
    const float* Wd = (const float*)d_in[6];
    const float* bd = (const float*)d_in[7];

    float* out_logp = (float*)d_out;                             // [N,64]
    float* out_emb  = (float*)d_out + (long long)N_NODES * OUTC; // [N,128]

    // workspace layout (16B-aligned regions)
    char* p = (char*)d_ws;
    float* dinv = (float*)p;                  p += sizeof(float) * N_NODES;
    unsigned short* Hb = (unsigned short*)p;  p += sizeof(short) * (size_t)(N_NODES + 4) * C; // +4 rows (ZROW pad)
    unsigned short* aggb = (unsigned short*)p; p += sizeof(short) * (size_t)N_NODES * C;      // bf16 h1
    int*   off   = (int*)p;                   p += sizeof(int) * (N_NODES + 4);
    int*   histG = (int*)p;                   p += sizeof(int) * SCM;
    int*   base  = (int*)p;                   p += sizeof(int) * SCM;
    int*   bsum  = (int*)p;                   p += sizeof(int) * 64;
    int*   tmp   = (int*)p;                   p += sizeof(int) * (size_t)E_EDGES;
    int*   csr   = (int*)p;                   p += sizeof(int) * (size_t)E_EDGES;
    uint4* Wp1   = (uint4*)p;                 p += sizeof(uint4) * 2048;
    uint4* Wp2   = (uint4*)p;                 p += sizeof(uint4) * 2048;

    // --- CSR build (also produces off[] and dinv[]) + W packs (+ZROW zero) ---
    k_hist<<<CB_BLOCKS, CB_THREADS, 0, stream>>>(coli, histG);
    k_packW<<<9, 256, 0, stream>>>(W1, Wp1, (uint4*)Hb);   // block 8 zeroes ZROW
    k_packW<<<8, 256, 0, stream>>>(W2, Wp2, nullptr);
    k_scanA<<<NSB, S1B, 0, stream>>>(histG, base, bsum);
    k_scanB<<<1, 64, 0, stream>>>(bsum);
    k_scanC<<<NSB, S1B, 0, stream>>>(base, bsum);
    k_coarse<<<CB_BLOCKS, CB_THREADS, 0, stream>>>(rowi, coli, base, tmp);
    k_fine<<<NBKT, 256, 0, stream>>>(tmp, base, csr, off, dinv);

    const int GB = (N_NODES + 63) / 64;          // 1563
    const int AB = (N_NODES * 16 + 255) / 256;   // 6250 (16 lanes per node)
    // --- conv1: H1b = (x@W1)*dinv -> gather-agg -> relu -> bf16 aggb ---
    k_gemm_mfma<false><<<GB, 256, 0, stream>>>(x, Wp1, dinv, Hb);
    k_aggregate<true><<<AB, 256, 0, stream>>>((const uint4*)Hb, csr, off, dinv, b1, aggb);
    // --- conv2: H2b = (aggb@W2)*dinv -> gather-agg -> normalize -> out_emb ---
    k_gemm_mfma<true><<<GB, 256, 0, stream>>>(aggb, Wp2, dinv, Hb);
    k_aggregate<false><<<AB, 256, 0, stream>>>((const uint4*)Hb, csr, off, dinv, b2, out_emb);
    // --- decode: logp = log_softmax(out_emb@Wd + bd) ---
    k_decode<<<GB, 256, 0, stream>>>(out_emb, Wd, bd, out_logp);
}